// Round 2
// baseline (1979.482 us; speedup 1.0000x reference)
//
#include <hip/hip_runtime.h>
#include <cstdint>
#include <cstddef>

// Problem constants (from reference): N=100000, F_IN=512, HID=256, C=64, E=3.2e6, K=5
#define NF_IN 512
#define NHID 256
#define NC 64

// ---------------- degree / CSR ----------------
__global__ void k_hist(const int* __restrict__ dst, int* __restrict__ cnt, int e_total){
  int e = blockIdx.x*256 + threadIdx.x;
  if (e < e_total) atomicAdd(&cnt[dst[e]], 1);
}

__global__ void k_dinv(const int* __restrict__ cnt, float* __restrict__ dinv, int n){
  int i = blockIdx.x*256 + threadIdx.x;
  if (i < n) dinv[i] = 1.0f / sqrtf((float)(cnt[i] + 1));   // +1 self-loop; exact, not rsqrt approx
}

// block partial sums (chunk = 1024 per block)
__global__ void k_scanA(const int* __restrict__ in, int n, int* __restrict__ bsum){
  __shared__ int P[256];
  int t = threadIdx.x;
  int base = blockIdx.x*1024 + t*4;
  int s = 0;
  #pragma unroll
  for (int j=0;j<4;j++) if (base+j < n) s += in[base+j];
  P[t] = s; __syncthreads();
  for (int o=128;o>0;o>>=1){ if (t<o) P[t]+=P[t+o]; __syncthreads(); }
  if (t==0) bsum[blockIdx.x] = P[0];
}

// single-block in-place exclusive scan (n <= 256*chunk)
__global__ void k_scan1(int* __restrict__ data, int n){
  __shared__ int P[256];
  int t = threadIdx.x;
  int chunk = (n + 255) >> 8;
  int base = t*chunk;
  int s = 0;
  for (int j=0;j<chunk;j++) if (base+j<n) s += data[base+j];
  P[t]=s; __syncthreads();
  for (int o=1;o<256;o<<=1){
    int v = (t>=o)? P[t-o]:0; __syncthreads();
    P[t]+=v; __syncthreads();
  }
  int run = (t>0)? P[t-1] : 0;
  for (int j=0;j<chunk;j++) if (base+j<n){ int v = data[base+j]; data[base+j]=run; run+=v; }
}

__global__ void k_scanC(const int* __restrict__ in, int n, const int* __restrict__ bsum,
                        int* __restrict__ rowptr, int* __restrict__ cursor){
  __shared__ int P[256];
  int t = threadIdx.x;
  int base = blockIdx.x*1024 + t*4;
  int loc[4]; int s=0;
  #pragma unroll
  for (int j=0;j<4;j++){ loc[j] = (base+j<n)? in[base+j]:0; s+=loc[j]; }
  P[t]=s; __syncthreads();
  for (int o=1;o<256;o<<=1){
    int v=(t>=o)?P[t-o]:0; __syncthreads(); P[t]+=v; __syncthreads();
  }
  int run = ((t>0)?P[t-1]:0) + bsum[blockIdx.x];
  #pragma unroll
  for (int j=0;j<4;j++) if (base+j<n){ rowptr[base+j]=run; cursor[base+j]=run; run+=loc[j]; }
}

__global__ void k_csr(const int* __restrict__ src, const int* __restrict__ dst,
                      int* __restrict__ cursor, int* __restrict__ csr, int e_total){
  int e = blockIdx.x*256 + threadIdx.x;
  if (e < e_total){ int p = atomicAdd(&cursor[dst[e]],1); csr[p] = src[e]; }
}

// ---------------- tiled fp32 GEMM: C[M x 64*gridDim.y] = A[M x K] @ B[K x ldb], epilogue *dinv[row] ----------------
__global__ __launch_bounds__(256) void k_gemm(const float* __restrict__ A, int lda,
    const float* __restrict__ B, int ldb, float* __restrict__ C, int ldc,
    int M, int K, const float* __restrict__ dinv){
  __shared__ float As[16*68];   // [k][m], padded stride 68 (16B-aligned, conflict-free)
  __shared__ float Bs[16*64];   // [k][n]
  int t = threadIdx.x;
  int m0 = blockIdx.x*64, n0 = blockIdx.y*64;
  int tx = t & 15, ty = t >> 4;
  float acc[4][4] = {};
  int arow = m0 + (t>>2); if (arow >= M) arow = M-1;
  const float* aptr = A + (size_t)arow*lda + (t&3)*4;
  const float* bptr = B + (size_t)(t>>4)*ldb + n0 + (t&15)*4;
  for (int k0=0; k0<K; k0+=16){
    float4 av = *(const float4*)(aptr + k0);
    float4 bv = *(const float4*)(bptr + (size_t)k0*ldb);
    __syncthreads();
    int ak = (t&3)*4, ar = t>>2;
    As[(ak+0)*68 + ar] = av.x;
    As[(ak+1)*68 + ar] = av.y;
    As[(ak+2)*68 + ar] = av.z;
    As[(ak+3)*68 + ar] = av.w;
    *(float4*)&Bs[(t>>4)*64 + (t&15)*4] = bv;
    __syncthreads();
    #pragma unroll
    for (int kk=0;kk<16;kk++){
      float4 a4 = *(const float4*)&As[kk*68 + (ty<<2)];
      float4 b4 = *(const float4*)&Bs[(kk<<6) + (tx<<2)];
      float aa[4] = {a4.x,a4.y,a4.z,a4.w};
      float bb[4] = {b4.x,b4.y,b4.z,b4.w};
      #pragma unroll
      for (int i=0;i<4;i++)
        #pragma unroll
        for (int j=0;j<4;j++) acc[i][j] += aa[i]*bb[j];
    }
  }
  #pragma unroll
  for (int i=0;i<4;i++){
    int row = m0 + (ty<<2) + i;
    if (row < M){
      float sc = dinv ? dinv[row] : 1.0f;
      float4 vv; vv.x=acc[i][0]*sc; vv.y=acc[i][1]*sc; vv.z=acc[i][2]*sc; vv.w=acc[i][3]*sc;
      *(float4*)&C[(size_t)row*ldc + n0 + (tx<<2)] = vv;
    }
  }
}

// ---------------- GCN aggregation: out[i] = act(dinv[i]*(sum_{s in N(i)} u[s] + u[i]) + b) ----------------
// u rows already pre-scaled by dinv (GEMM epilogue). 256-channel version: wave/node, float4/lane.
__global__ __launch_bounds__(256) void k_agg1(const float* __restrict__ u,
    const int* __restrict__ rowptr, const int* __restrict__ cnt,
    const int* __restrict__ csr, const float* __restrict__ dinv,
    const float* __restrict__ bias, float* __restrict__ outp, int n){
  int wid = blockIdx.x*4 + (threadIdx.x>>6);
  int lane = threadIdx.x & 63;
  if (wid >= n) return;
  const float4* up = (const float4*)u;
  float4 a = up[(size_t)wid*64 + lane];       // self term
  float ax=a.x, ay=a.y, az=a.z, aw=a.w;
  int beg = rowptr[wid], num = cnt[wid];
  int e = 0;
  for (; e+8 <= num; e+=8){
    int s[8];
    #pragma unroll
    for (int q=0;q<8;q++) s[q] = csr[beg+e+q];
    #pragma unroll
    for (int q=0;q<8;q++){
      float4 v = up[(size_t)s[q]*64 + lane];
      ax+=v.x; ay+=v.y; az+=v.z; aw+=v.w;
    }
  }
  for (; e<num; e++){
    int sN = csr[beg+e];
    float4 v = up[(size_t)sN*64 + lane];
    ax+=v.x; ay+=v.y; az+=v.z; aw+=v.w;
  }
  float di = dinv[wid];
  float4 b = ((const float4*)bias)[lane];
  float4 r;
  r.x = fmaxf(di*ax + b.x, 0.f);
  r.y = fmaxf(di*ay + b.y, 0.f);
  r.z = fmaxf(di*az + b.z, 0.f);
  r.w = fmaxf(di*aw + b.w, 0.f);
  ((float4*)outp)[(size_t)wid*64 + lane] = r;
}

// 64-channel version, no relu
__global__ __launch_bounds__(256) void k_agg2(const float* __restrict__ u,
    const int* __restrict__ rowptr, const int* __restrict__ cnt,
    const int* __restrict__ csr, const float* __restrict__ dinv,
    const float* __restrict__ bias, float* __restrict__ outp, int n){
  int wid = blockIdx.x*4 + (threadIdx.x>>6);
  int lane = threadIdx.x & 63;
  if (wid >= n) return;
  float acc = u[(size_t)wid*64 + lane];
  int beg = rowptr[wid], num = cnt[wid];
  int e = 0;
  for (; e+8 <= num; e+=8){
    int s[8];
    #pragma unroll
    for (int q=0;q<8;q++) s[q] = csr[beg+e+q];
    #pragma unroll
    for (int q=0;q<8;q++) acc += u[(size_t)s[q]*64 + lane];
  }
  for (; e<num; e++){
    int sN = csr[beg+e];
    acc += u[(size_t)sN*64 + lane];
  }
  outp[(size_t)wid*64 + lane] = dinv[wid]*acc + bias[lane];
}

// ---------------- g score + sort keys ----------------
__global__ void k_gscore(const float* __restrict__ x1, const float* __restrict__ Wp,
    const float* __restrict__ bp, float* __restrict__ g,
    unsigned* __restrict__ keys, unsigned* __restrict__ vals, int n){
  int wid = blockIdx.x*4 + (threadIdx.x>>6);
  int lane = threadIdx.x & 63;
  if (wid >= n) return;
  float v = x1[(size_t)wid*64 + lane] * Wp[lane];
  for (int o=32;o>0;o>>=1) v += __shfl_xor(v, o);
  if (lane == 0){
    float gg = v + bp[0];
    g[wid] = gg;
    unsigned u = __float_as_uint(gg);
    u = (u>>31) ? ~u : (u | 0x80000000u);   // monotone float->uint
    keys[wid] = u; vals[wid] = (unsigned)wid;
  }
}

// ---------------- stable 4-bit LSD radix sort (1024 elems/block) ----------------
__global__ void k_rhist(const unsigned* __restrict__ keys, int shift,
                        int* __restrict__ ghist, int n){
  __shared__ int h[16];
  int t = threadIdx.x;
  if (t < 16) h[t] = 0;
  __syncthreads();
  int base = blockIdx.x*1024 + t*4;
  #pragma unroll
  for (int j=0;j<4;j++)
    if (base+j < n){ int d = (keys[base+j]>>shift)&15; atomicAdd(&h[d],1); }
  __syncthreads();
  if (t < 16) ghist[t*gridDim.x + blockIdx.x] = h[t];
}

__global__ void k_rscatter(const unsigned* __restrict__ keys, const unsigned* __restrict__ vals,
                           int shift, const int* __restrict__ gbase,
                           unsigned* __restrict__ okeys, unsigned* __restrict__ ovals, int n){
  __shared__ int F[16*256];
  __shared__ int P[256];
  int t = threadIdx.x;
  int base = blockIdx.x*1024 + t*4;
  unsigned k[4]; int d[4];
  #pragma unroll
  for (int j=0;j<4;j++){
    bool ok = (base+j < n);
    k[j] = ok ? keys[base+j] : 0u;
    d[j] = (int)((k[j]>>shift)&15u);
    if (!ok) d[j] = -1;
  }
  #pragma unroll
  for (int dig=0;dig<16;dig++){
    int c = 0;
    #pragma unroll
    for (int j=0;j<4;j++) if (d[j]==dig) c++;
    F[dig*256 + t] = c;
  }
  __syncthreads();
  // exclusive scan of F[4096] flat (digit-major layout; flat order == stable rank order)
  int loc[16]; int s = 0;
  #pragma unroll
  for (int q=0;q<16;q++){ loc[q] = F[t*16+q]; s += loc[q]; }
  P[t] = s; __syncthreads();
  for (int o=1;o<256;o<<=1){
    int v = (t>=o)? P[t-o]:0; __syncthreads();
    P[t] += v; __syncthreads();
  }
  int run = (t>0)? P[t-1] : 0;
  #pragma unroll
  for (int q=0;q<16;q++){ F[t*16+q] = run; run += loc[q]; }
  __syncthreads();
  #pragma unroll
  for (int j=0;j<4;j++){
    if (base+j < n){
      int dd = d[j];
      int r = 0;
      #pragma unroll
      for (int jj=0;jj<4;jj++) if (jj<j && d[jj]==dd) r++;
      int pos = gbase[dd*gridDim.x + blockIdx.x] + (F[dd*256 + t] - F[dd*256]) + r;
      okeys[pos] = k[j];
      ovals[pos] = vals[base+j];
    }
  }
}

// ---------------- sorted seq build, inverse perm ----------------
// sidx = vals after final pass: sidx[p] = original node index at sorted position p
__global__ void k_ssx(const unsigned* __restrict__ sidx, const float* __restrict__ g,
                      const float* __restrict__ x1, float* __restrict__ ssx,
                      int* __restrict__ inv, int n){
  int idx = blockIdx.x*256 + threadIdx.x;
  if (idx < n*64){
    int p = idx>>6, c = idx&63;
    int j = (int)sidx[p];
    ssx[idx] = g[j] * x1[(size_t)j*64 + c];
    if (c==0) inv[j] = p;
  }
}

// conv weight transpose [co][ci][k] -> [k][ci][co]
__global__ void k_wt(const float* __restrict__ cw1, const float* __restrict__ cw2,
                     float* __restrict__ wT1, float* __restrict__ wT2){
  int idx = blockIdx.x*256 + threadIdx.x;
  if (idx < 2*20480){
    const float* s = (idx < 20480) ? cw1 : cw2;
    float* o = (idx < 20480) ? wT1 : wT2;
    int i = idx % 20480;
    int kk = i % 5, ci = (i/5) % 64, co = i / 320;
    o[((kk<<6)+ci)*64 + co] = s[i];
  }
}

// ---------------- direct conv1d, C=64, K=5, SAME; 128 rows/block, 8 rows x 4 cout per thread ----------------
__global__ __launch_bounds__(256) void k_conv(const float* __restrict__ inp,
    const float* __restrict__ wT, const float* __restrict__ bias,
    float* __restrict__ outp, int n, int do_relu){
  __shared__ float xin[132*65];    // rows r0-2 .. r0+129, stride 65 (conflict-free)
  int t = threadIdx.x;
  int r0 = blockIdx.x*128;
  for (int idx=t; idx<132*64; idx+=256){
    int r = idx>>6, c = idx&63;
    int gr = r0 + r - 2;
    xin[r*65 + c] = (gr>=0 && gr<n) ? inp[(size_t)gr*64 + c] : 0.f;
  }
  __syncthreads();
  int rg = t & 15, cg = t >> 4;     // rows rg+16*rr, couts cg*4..+3
  float acc[8][4] = {};
  for (int k=0;k<5;k++){
    for (int ci=0;ci<64;ci++){
      float4 w = *(const float4*)&wT[((k<<6)+ci)*64 + (cg<<2)];
      #pragma unroll
      for (int rr=0;rr<8;rr++){
        float xv = xin[(rg + (rr<<4) + k)*65 + ci];
        acc[rr][0] += xv*w.x; acc[rr][1] += xv*w.y;
        acc[rr][2] += xv*w.z; acc[rr][3] += xv*w.w;
      }
    }
  }
  float4 b = ((const float4*)bias)[cg];
  #pragma unroll
  for (int rr=0;rr<8;rr++){
    int row = r0 + rg + (rr<<4);
    if (row < n){
      float4 v;
      v.x = acc[rr][0]+b.x; v.y = acc[rr][1]+b.y; v.z = acc[rr][2]+b.z; v.w = acc[rr][3]+b.w;
      if (do_relu){ v.x=fmaxf(v.x,0.f); v.y=fmaxf(v.y,0.f); v.z=fmaxf(v.z,0.f); v.w=fmaxf(v.w,0.f); }
      *(float4*)&outp[(size_t)row*64 + (cg<<2)] = v;
    }
  }
}

// concat [x1 | y2[inv]] -> cat[N,128]
__global__ void k_cat(const float* __restrict__ x1, const float* __restrict__ y2,
                      const int* __restrict__ inv, float* __restrict__ cat, int n){
  int idx = blockIdx.x*256 + threadIdx.x;
  if (idx < n*128){
    int i = idx>>7, c = idx&127;
    cat[idx] = (c < 64) ? x1[(size_t)i*64 + c] : y2[(size_t)inv[i]*64 + (c-64)];
  }
}

__global__ void k_lsm(const float* __restrict__ logits, const float* __restrict__ bl,
                      float* __restrict__ outp, int n){
  int wid = blockIdx.x*4 + (threadIdx.x>>6);
  int lane = threadIdx.x & 63;
  if (wid >= n) return;
  float v = logits[(size_t)wid*64 + lane] + bl[lane];
  float m = v;
  for (int o=32;o>0;o>>=1) m = fmaxf(m, __shfl_xor(m, o));
  float ex = expf(v - m);
  float s = ex;
  for (int o=32;o>0;o>>=1) s += __shfl_xor(s, o);
  outp[(size_t)wid*64 + lane] = v - m - logf(s);
}

// ---------------- launch ----------------
extern "C" void kernel_launch(void* const* d_in, const int* in_sizes, int n_in,
                              void* d_out, int out_size, void* d_ws, size_t ws_size,
                              hipStream_t stream) {
  const float* x   = (const float*)d_in[0];
  const int*   ei  = (const int*)d_in[1];
  const float* W1  = (const float*)d_in[2];
  const float* b1  = (const float*)d_in[3];
  const float* W2  = (const float*)d_in[4];
  const float* b2  = (const float*)d_in[5];
  const float* Wp  = (const float*)d_in[6];
  const float* bp  = (const float*)d_in[7];
  const float* cw1 = (const float*)d_in[8];
  const float* cb1 = (const float*)d_in[9];
  const float* cw2 = (const float*)d_in[10];
  const float* cb2 = (const float*)d_in[11];
  const float* Wl  = (const float*)d_in[12];
  const float* bl  = (const float*)d_in[13];
  float* out = (float*)d_out;

  const int n = in_sizes[0] / NF_IN;        // 100000
  const int e_total = in_sizes[1] / 2;      // 3200000
  const int* srcp = ei;
  const int* dstp = ei + e_total;

  // workspace carve-up (~223 MB total)
  char* ws = (char*)d_ws;
  size_t off = 0;
  auto take = [&](size_t bytes)->char* {
    char* p = ws + off; off = (off + bytes + 255) & ~(size_t)255; return p;
  };
  const int NB = (n + 1023) / 1024;         // radix/scan blocks (98)
  int*      cnt    = (int*)     take((size_t)n*4);
  int*      rowptr = (int*)     take((size_t)n*4);
  int*      cursor = (int*)     take((size_t)n*4);
  float*    dinv   = (float*)   take((size_t)n*4);
  float*    g      = (float*)   take((size_t)n*4);
  int*      inv    = (int*)     take((size_t)n*4);
  unsigned* keys0  = (unsigned*)take((size_t)n*4);
  unsigned* vals0  = (unsigned*)take((size_t)n*4);
  unsigned* keys1  = (unsigned*)take((size_t)n*4);
  unsigned* vals1  = (unsigned*)take((size_t)n*4);
  int*      ghist  = (int*)     take((size_t)(16*NB)*4);
  int*      bsum   = (int*)     take((size_t)NB*4 + 256);
  int*      csr    = (int*)     take((size_t)e_total*4);
  float*    wT1    = (float*)   take(20480*4);
  float*    wT2    = (float*)   take(20480*4);
  float*    bigA   = (float*)   take((size_t)n*256*4);
  float*    bigB   = (float*)   take((size_t)n*256*4);
  // phase-aliased views
  float* u1  = bigA;                         // GEMM1 out (dinv-scaled)
  float* h   = bigB;                         // relu(gcn1)
  float* u2  = bigA;                         // GEMM2 out (u1 dead)
  float* x1  = bigA + (size_t)n*64;          // gcn2 out
  float* ssx = bigA + (size_t)n*128;         // sorted scaled seq
  float* y1  = bigA + (size_t)n*192;         // conv1 out
  float* y2  = bigB;                         // conv2 out (h dead)
  float* cat = bigB + (size_t)n*64;          // [N,128]
  float* logits = bigB + (size_t)n*192;

  const int nb64  = (n + 63) / 64;           // 1563
  const int nbAgg = (n + 3) / 4;             // 25000 (4 waves/block)
  const int nbE   = (e_total + 255) / 256;

  hipMemsetAsync(cnt, 0, (size_t)n*4, stream);
  k_hist<<<nbE, 256, 0, stream>>>(dstp, cnt, e_total);
  k_dinv<<<(n+255)/256, 256, 0, stream>>>(cnt, dinv, n);
  k_scanA<<<NB, 256, 0, stream>>>(cnt, n, bsum);
  k_scan1<<<1, 256, 0, stream>>>(bsum, NB);
  k_scanC<<<NB, 256, 0, stream>>>(cnt, n, bsum, rowptr, cursor);
  k_csr<<<nbE, 256, 0, stream>>>(srcp, dstp, cursor, csr, e_total);

  // GCN layer 1: u1 = dinv .* (x @ W1); h = relu(agg(u1) + b1)
  k_gemm<<<dim3(nb64, 4), 256, 0, stream>>>(x, NF_IN, W1, NHID, u1, NHID, n, NF_IN, dinv);
  k_agg1<<<nbAgg, 256, 0, stream>>>(u1, rowptr, cnt, csr, dinv, b1, h, n);

  // GCN layer 2: u2 = dinv .* (h @ W2); x1 = agg(u2) + b2
  k_gemm<<<dim3(nb64, 1), 256, 0, stream>>>(h, NHID, W2, NC, u2, NC, n, NHID, dinv);
  k_agg2<<<nbAgg, 256, 0, stream>>>(u2, rowptr, cnt, csr, dinv, b2, x1, n);

  // score + sort keys
  k_gscore<<<nbAgg, 256, 0, stream>>>(x1, Wp, bp, g, keys0, vals0, n);

  // stable radix sort, 8 x 4-bit passes (ends back in keys0/vals0)
  unsigned *ka = keys0, *va = vals0, *kb = keys1, *vb = vals1;
  for (int p = 0; p < 8; p++){
    k_rhist<<<NB, 256, 0, stream>>>(ka, p*4, ghist, n);
    k_scan1<<<1, 256, 0, stream>>>(ghist, 16*NB);
    k_rscatter<<<NB, 256, 0, stream>>>(ka, va, p*4, ghist, kb, vb, n);
    unsigned* tk = ka; ka = kb; kb = tk;
    unsigned* tv = va; va = vb; vb = tv;
  }

  // sorted sequence + inverse permutation  (vals = sorted node indices — NOT keys)
  k_ssx<<<(n*64+255)/256, 256, 0, stream>>>(va, g, x1, ssx, inv, n);

  // conv1d x2
  k_wt<<<(2*20480+255)/256, 256, 0, stream>>>(cw1, cw2, wT1, wT2);
  k_conv<<<(n+127)/128, 256, 0, stream>>>(ssx, wT1, cb1, y1, n, 1);
  k_conv<<<(n+127)/128, 256, 0, stream>>>(y1, wT2, cb2, y2, n, 0);

  // concat -> GEMM -> log_softmax
  k_cat<<<(n*128+255)/256, 256, 0, stream>>>(x1, y2, inv, cat, n);
  k_gemm<<<dim3(nb64, 1), 256, 0, stream>>>(cat, 2*NC, Wl, NC, logits, NC, n, 2*NC, nullptr);
  k_lsm<<<nbAgg, 256, 0, stream>>>(logits, bl, out, n);
}

// Round 3
// 1958.471 us; speedup vs baseline: 1.0107x; 1.0107x over previous
//
#include <hip/hip_runtime.h>
#include <cstdint>
#include <cstddef>

// Problem constants (from reference): N=100000, F_IN=512, HID=256, C=64, E=3.2e6, K=5
#define NF_IN 512
#define NHID 256
#define NC 64

// ---------------- degree / CSR ----------------
__global__ void k_hist(const int* __restrict__ dst, int* __restrict__ cnt, int e_total){
  int e = blockIdx.x*256 + threadIdx.x;
  if (e < e_total) atomicAdd(&cnt[dst[e]], 1);
}

__global__ void k_dinv(const int* __restrict__ cnt, float* __restrict__ dinv, int n){
  int i = blockIdx.x*256 + threadIdx.x;
  if (i < n) dinv[i] = 1.0f / sqrtf((float)(cnt[i] + 1));   // +1 self-loop; exact, not rsqrt approx
}

// block partial sums (chunk = 1024 per block)
__global__ void k_scanA(const int* __restrict__ in, int n, int* __restrict__ bsum){
  __shared__ int P[256];
  int t = threadIdx.x;
  int base = blockIdx.x*1024 + t*4;
  int s = 0;
  #pragma unroll
  for (int j=0;j<4;j++) if (base+j < n) s += in[base+j];
  P[t] = s; __syncthreads();
  for (int o=128;o>0;o>>=1){ if (t<o) P[t]+=P[t+o]; __syncthreads(); }
  if (t==0) bsum[blockIdx.x] = P[0];
}

// single-block in-place exclusive scan (n <= 256*chunk)
__global__ void k_scan1(int* __restrict__ data, int n){
  __shared__ int P[256];
  int t = threadIdx.x;
  int chunk = (n + 255) >> 8;
  int base = t*chunk;
  int s = 0;
  for (int j=0;j<chunk;j++) if (base+j<n) s += data[base+j];
  P[t]=s; __syncthreads();
  for (int o=1;o<256;o<<=1){
    int v = (t>=o)? P[t-o]:0; __syncthreads();
    P[t]+=v; __syncthreads();
  }
  int run = (t>0)? P[t-1] : 0;
  for (int j=0;j<chunk;j++) if (base+j<n){ int v = data[base+j]; data[base+j]=run; run+=v; }
}

__global__ void k_scanC(const int* __restrict__ in, int n, const int* __restrict__ bsum,
                        int* __restrict__ rowptr, int* __restrict__ cursor){
  __shared__ int P[256];
  int t = threadIdx.x;
  int base = blockIdx.x*1024 + t*4;
  int loc[4]; int s=0;
  #pragma unroll
  for (int j=0;j<4;j++){ loc[j] = (base+j<n)? in[base+j]:0; s+=loc[j]; }
  P[t]=s; __syncthreads();
  for (int o=1;o<256;o<<=1){
    int v=(t>=o)?P[t-o]:0; __syncthreads(); P[t]+=v; __syncthreads();
  }
  int run = ((t>0)?P[t-1]:0) + bsum[blockIdx.x];
  #pragma unroll
  for (int j=0;j<4;j++) if (base+j<n){ rowptr[base+j]=run; cursor[base+j]=run; run+=loc[j]; }
}

__global__ void k_csr(const int* __restrict__ src, const int* __restrict__ dst,
                      int* __restrict__ cursor, int* __restrict__ csr, int e_total){
  int e = blockIdx.x*256 + threadIdx.x;
  if (e < e_total){ int p = atomicAdd(&cursor[dst[e]],1); csr[p] = src[e]; }
}

// ---------------- fp32 GEMM 128x128 tile, 8x8 microtile ----------------
// A[M x K] row-major (lda=K), B[K x N] row-major (ldb=N), C row-major (ldc).
// Requires K % 16 == 0, N tile full (N % 128 == 0 for the used blocks).
// A staged TRANSPOSED in LDS [k][m] pad 132 -> fragment reads are b128 with
// broadcast lane patterns (conflict-free). Epilogue scales row by dinv.
__global__ __launch_bounds__(256, 2) void k_gemm128(const float* __restrict__ A, int lda,
    const float* __restrict__ B, int ldb, float* __restrict__ C, int ldc,
    int M, int K, const float* __restrict__ dinv){
  __shared__ float As[16*132];   // [k][m], pad 132 (16B aligned rows: 132*4=528=33*16)
  __shared__ float Bs[16*128];   // [k][n]
  int t = threadIdx.x;
  int tx = t & 15, ty = t >> 4;            // 16x16 thread grid
  int m0 = blockIdx.x*128, n0 = blockIdx.y*128;

  // A staging: thread t -> row t>>1 (0..127), k-slice (t&1)*8
  int arow = t >> 1, kb = (t & 1) * 8;
  int ga = m0 + arow; if (ga >= M) ga = M - 1;
  const float* aptr = A + (size_t)ga*lda + kb;
  // B staging: thread t -> k-row t>>4 (0..15), cols (t&15)*8
  int brow = t >> 4, bcol = (t & 15) * 8;
  const float* bptr = B + (size_t)brow*ldb + n0 + bcol;

  float4 a0 = *(const float4*)(aptr);
  float4 a1 = *(const float4*)(aptr + 4);
  float4 b0 = *(const float4*)(bptr);
  float4 b1 = *(const float4*)(bptr + 4);

  float acc[8][8] = {};
  for (int k0 = 0; k0 < K; k0 += 16){
    __syncthreads();
    As[(kb+0)*132 + arow] = a0.x;
    As[(kb+1)*132 + arow] = a0.y;
    As[(kb+2)*132 + arow] = a0.z;
    As[(kb+3)*132 + arow] = a0.w;
    As[(kb+4)*132 + arow] = a1.x;
    As[(kb+5)*132 + arow] = a1.y;
    As[(kb+6)*132 + arow] = a1.z;
    As[(kb+7)*132 + arow] = a1.w;
    *(float4*)&Bs[brow*128 + bcol]     = b0;
    *(float4*)&Bs[brow*128 + bcol + 4] = b1;
    __syncthreads();
    if (k0 + 16 < K){
      a0 = *(const float4*)(aptr + k0 + 16);
      a1 = *(const float4*)(aptr + k0 + 20);
      b0 = *(const float4*)(bptr + (size_t)(k0+16)*ldb);
      b1 = *(const float4*)(bptr + (size_t)(k0+16)*ldb + 4);
    }
    #pragma unroll
    for (int kk=0;kk<16;kk++){
      float4 ra0 = *(const float4*)&As[kk*132 + ty*4];
      float4 ra1 = *(const float4*)&As[kk*132 + 64 + ty*4];
      float4 rb0 = *(const float4*)&Bs[kk*128 + tx*4];
      float4 rb1 = *(const float4*)&Bs[kk*128 + 64 + tx*4];
      float ar[8] = {ra0.x,ra0.y,ra0.z,ra0.w, ra1.x,ra1.y,ra1.z,ra1.w};
      float br[8] = {rb0.x,rb0.y,rb0.z,rb0.w, rb1.x,rb1.y,rb1.z,rb1.w};
      #pragma unroll
      for (int i=0;i<8;i++)
        #pragma unroll
        for (int j=0;j<8;j++) acc[i][j] += ar[i]*br[j];
    }
  }
  #pragma unroll
  for (int i=0;i<8;i++){
    int row = m0 + ((i<4)? (ty*4 + i) : (64 + ty*4 + (i-4)));
    if (row < M){
      float sc = dinv ? dinv[row] : 1.0f;
      float4 v0, v1;
      v0.x=acc[i][0]*sc; v0.y=acc[i][1]*sc; v0.z=acc[i][2]*sc; v0.w=acc[i][3]*sc;
      v1.x=acc[i][4]*sc; v1.y=acc[i][5]*sc; v1.z=acc[i][6]*sc; v1.w=acc[i][7]*sc;
      *(float4*)&C[(size_t)row*ldc + n0 + tx*4]      = v0;
      *(float4*)&C[(size_t)row*ldc + n0 + 64 + tx*4] = v1;
    }
  }
}

// ---------------- tiled fp32 GEMM (64-wide N), kept for GEMM2/final ----------------
__global__ __launch_bounds__(256) void k_gemm(const float* __restrict__ A, int lda,
    const float* __restrict__ B, int ldb, float* __restrict__ C, int ldc,
    int M, int K, const float* __restrict__ dinv){
  __shared__ float As[16*68];   // [k][m], padded stride 68
  __shared__ float Bs[16*64];   // [k][n]
  int t = threadIdx.x;
  int m0 = blockIdx.x*64, n0 = blockIdx.y*64;
  int tx = t & 15, ty = t >> 4;
  float acc[4][4] = {};
  int arow = m0 + (t>>2); if (arow >= M) arow = M-1;
  const float* aptr = A + (size_t)arow*lda + (t&3)*4;
  const float* bptr = B + (size_t)(t>>4)*ldb + n0 + (t&15)*4;
  for (int k0=0; k0<K; k0+=16){
    float4 av = *(const float4*)(aptr + k0);
    float4 bv = *(const float4*)(bptr + (size_t)k0*ldb);
    __syncthreads();
    int ak = (t&3)*4, ar = t>>2;
    As[(ak+0)*68 + ar] = av.x;
    As[(ak+1)*68 + ar] = av.y;
    As[(ak+2)*68 + ar] = av.z;
    As[(ak+3)*68 + ar] = av.w;
    *(float4*)&Bs[(t>>4)*64 + (t&15)*4] = bv;
    __syncthreads();
    #pragma unroll
    for (int kk=0;kk<16;kk++){
      float4 a4 = *(const float4*)&As[kk*68 + (ty<<2)];
      float4 b4 = *(const float4*)&Bs[(kk<<6) + (tx<<2)];
      float aa[4] = {a4.x,a4.y,a4.z,a4.w};
      float bb[4] = {b4.x,b4.y,b4.z,b4.w};
      #pragma unroll
      for (int i=0;i<4;i++)
        #pragma unroll
        for (int j=0;j<4;j++) acc[i][j] += aa[i]*bb[j];
    }
  }
  #pragma unroll
  for (int i=0;i<4;i++){
    int row = m0 + (ty<<2) + i;
    if (row < M){
      float sc = dinv ? dinv[row] : 1.0f;
      float4 vv; vv.x=acc[i][0]*sc; vv.y=acc[i][1]*sc; vv.z=acc[i][2]*sc; vv.w=acc[i][3]*sc;
      *(float4*)&C[(size_t)row*ldc + n0 + (tx<<2)] = vv;
    }
  }
}

// ---------------- GCN aggregation (256-ch): wave/node, float4/lane, 16-deep MLP ----------------
__global__ __launch_bounds__(256) void k_agg1(const float* __restrict__ u,
    const int* __restrict__ rowptr, const int* __restrict__ cnt,
    const int* __restrict__ csr, const float* __restrict__ dinv,
    const float* __restrict__ bias, float* __restrict__ outp, int n){
  int wid = blockIdx.x*4 + (threadIdx.x>>6);
  int lane = threadIdx.x & 63;
  if (wid >= n) return;
  const float4* up = (const float4*)u;
  float4 a = up[(size_t)wid*64 + lane];       // self term
  float ax=a.x, ay=a.y, az=a.z, aw=a.w;
  int beg = rowptr[wid], num = cnt[wid];
  int e = 0;
  for (; e+16 <= num; e+=16){
    int my = csr[beg + e + (lane & 15)];      // 16 indices, replicated across wave quarters
    float4 v[16];
    #pragma unroll
    for (int q=0;q<16;q++){ int s = __shfl(my, q); v[q] = up[(size_t)s*64 + lane]; }
    #pragma unroll
    for (int q=0;q<16;q++){ ax+=v[q].x; ay+=v[q].y; az+=v[q].z; aw+=v[q].w; }
  }
  for (; e+4 <= num; e+=4){
    int my = csr[beg + e + (lane & 3)];
    float4 v[4];
    #pragma unroll
    for (int q=0;q<4;q++){ int s = __shfl(my, q); v[q] = up[(size_t)s*64 + lane]; }
    #pragma unroll
    for (int q=0;q<4;q++){ ax+=v[q].x; ay+=v[q].y; az+=v[q].z; aw+=v[q].w; }
  }
  for (; e<num; e++){
    int sN = csr[beg+e];
    float4 v = up[(size_t)sN*64 + lane];
    ax+=v.x; ay+=v.y; az+=v.z; aw+=v.w;
  }
  float di = dinv[wid];
  float4 b = ((const float4*)bias)[lane];
  float4 r;
  r.x = fmaxf(di*ax + b.x, 0.f);
  r.y = fmaxf(di*ay + b.y, 0.f);
  r.z = fmaxf(di*az + b.z, 0.f);
  r.w = fmaxf(di*aw + b.w, 0.f);
  ((float4*)outp)[(size_t)wid*64 + lane] = r;
}

// 64-channel version, no relu, 16-deep
__global__ __launch_bounds__(256) void k_agg2(const float* __restrict__ u,
    const int* __restrict__ rowptr, const int* __restrict__ cnt,
    const int* __restrict__ csr, const float* __restrict__ dinv,
    const float* __restrict__ bias, float* __restrict__ outp, int n){
  int wid = blockIdx.x*4 + (threadIdx.x>>6);
  int lane = threadIdx.x & 63;
  if (wid >= n) return;
  float acc = u[(size_t)wid*64 + lane];
  int beg = rowptr[wid], num = cnt[wid];
  int e = 0;
  for (; e+16 <= num; e+=16){
    int my = csr[beg + e + (lane & 15)];
    float v[16];
    #pragma unroll
    for (int q=0;q<16;q++){ int s = __shfl(my, q); v[q] = u[(size_t)s*64 + lane]; }
    #pragma unroll
    for (int q=0;q<16;q++) acc += v[q];
  }
  for (; e+4 <= num; e+=4){
    int my = csr[beg + e + (lane & 3)];
    float v[4];
    #pragma unroll
    for (int q=0;q<4;q++){ int s = __shfl(my, q); v[q] = u[(size_t)s*64 + lane]; }
    #pragma unroll
    for (int q=0;q<4;q++) acc += v[q];
  }
  for (; e<num; e++){
    int sN = csr[beg+e];
    acc += u[(size_t)sN*64 + lane];
  }
  outp[(size_t)wid*64 + lane] = dinv[wid]*acc + bias[lane];
}

// ---------------- g score + sort keys ----------------
__global__ void k_gscore(const float* __restrict__ x1, const float* __restrict__ Wp,
    const float* __restrict__ bp, float* __restrict__ g,
    unsigned* __restrict__ keys, unsigned* __restrict__ vals, int n){
  int wid = blockIdx.x*4 + (threadIdx.x>>6);
  int lane = threadIdx.x & 63;
  if (wid >= n) return;
  float v = x1[(size_t)wid*64 + lane] * Wp[lane];
  for (int o=32;o>0;o>>=1) v += __shfl_xor(v, o);
  if (lane == 0){
    float gg = v + bp[0];
    g[wid] = gg;
    unsigned u = __float_as_uint(gg);
    u = (u>>31) ? ~u : (u | 0x80000000u);   // monotone float->uint
    keys[wid] = u; vals[wid] = (unsigned)wid;
  }
}

// ---------------- stable 4-bit LSD radix sort (1024 elems/block) ----------------
__global__ void k_rhist(const unsigned* __restrict__ keys, int shift,
                        int* __restrict__ ghist, int n){
  __shared__ int h[16];
  int t = threadIdx.x;
  if (t < 16) h[t] = 0;
  __syncthreads();
  int base = blockIdx.x*1024 + t*4;
  #pragma unroll
  for (int j=0;j<4;j++)
    if (base+j < n){ int d = (keys[base+j]>>shift)&15; atomicAdd(&h[d],1); }
  __syncthreads();
  if (t < 16) ghist[t*gridDim.x + blockIdx.x] = h[t];
}

__global__ void k_rscatter(const unsigned* __restrict__ keys, const unsigned* __restrict__ vals,
                           int shift, const int* __restrict__ gbase,
                           unsigned* __restrict__ okeys, unsigned* __restrict__ ovals, int n){
  __shared__ int F[16*256];
  __shared__ int P[256];
  int t = threadIdx.x;
  int base = blockIdx.x*1024 + t*4;
  unsigned k[4]; int d[4];
  #pragma unroll
  for (int j=0;j<4;j++){
    bool ok = (base+j < n);
    k[j] = ok ? keys[base+j] : 0u;
    d[j] = (int)((k[j]>>shift)&15u);
    if (!ok) d[j] = -1;
  }
  #pragma unroll
  for (int dig=0;dig<16;dig++){
    int c = 0;
    #pragma unroll
    for (int j=0;j<4;j++) if (d[j]==dig) c++;
    F[dig*256 + t] = c;
  }
  __syncthreads();
  // exclusive scan of F[4096] flat (digit-major layout; flat order == stable rank order)
  int loc[16]; int s = 0;
  #pragma unroll
  for (int q=0;q<16;q++){ loc[q] = F[t*16+q]; s += loc[q]; }
  P[t] = s; __syncthreads();
  for (int o=1;o<256;o<<=1){
    int v = (t>=o)? P[t-o]:0; __syncthreads();
    P[t] += v; __syncthreads();
  }
  int run = (t>0)? P[t-1] : 0;
  #pragma unroll
  for (int q=0;q<16;q++){ F[t*16+q] = run; run += loc[q]; }
  __syncthreads();
  #pragma unroll
  for (int j=0;j<4;j++){
    if (base+j < n){
      int dd = d[j];
      int r = 0;
      #pragma unroll
      for (int jj=0;jj<4;jj++) if (jj<j && d[jj]==dd) r++;
      int pos = gbase[dd*gridDim.x + blockIdx.x] + (F[dd*256 + t] - F[dd*256]) + r;
      okeys[pos] = k[j];
      ovals[pos] = vals[base+j];
    }
  }
}

// ---------------- sorted seq build, inverse perm ----------------
__global__ void k_ssx(const unsigned* __restrict__ sidx, const float* __restrict__ g,
                      const float* __restrict__ x1, float* __restrict__ ssx,
                      int* __restrict__ inv, int n){
  int idx = blockIdx.x*256 + threadIdx.x;
  if (idx < n*64){
    int p = idx>>6, c = idx&63;
    int j = (int)sidx[p];
    ssx[idx] = g[j] * x1[(size_t)j*64 + c];
    if (c==0) inv[j] = p;
  }
}

// conv weight transpose [co][ci][k] -> [k][ci][co]
__global__ void k_wt(const float* __restrict__ cw1, const float* __restrict__ cw2,
                     float* __restrict__ wT1, float* __restrict__ wT2){
  int idx = blockIdx.x*256 + threadIdx.x;
  if (idx < 2*20480){
    const float* s = (idx < 20480) ? cw1 : cw2;
    float* o = (idx < 20480) ? wT1 : wT2;
    int i = idx % 20480;
    int kk = i % 5, ci = (i/5) % 64, co = i / 320;
    o[((kk<<6)+ci)*64 + co] = s[i];
  }
}

// ---------------- direct conv1d, C=64, K=5, SAME ----------------
__global__ __launch_bounds__(256) void k_conv(const float* __restrict__ inp,
    const float* __restrict__ wT, const float* __restrict__ bias,
    float* __restrict__ outp, int n, int do_relu){
  __shared__ float xin[132*65];    // rows r0-2 .. r0+129, stride 65
  int t = threadIdx.x;
  int r0 = blockIdx.x*128;
  for (int idx=t; idx<132*64; idx+=256){
    int r = idx>>6, c = idx&63;
    int gr = r0 + r - 2;
    xin[r*65 + c] = (gr>=0 && gr<n) ? inp[(size_t)gr*64 + c] : 0.f;
  }
  __syncthreads();
  int rg = t & 15, cg = t >> 4;
  float acc[8][4] = {};
  for (int k=0;k<5;k++){
    for (int ci=0;ci<64;ci++){
      float4 w = *(const float4*)&wT[((k<<6)+ci)*64 + (cg<<2)];
      #pragma unroll
      for (int rr=0;rr<8;rr++){
        float xv = xin[(rg + (rr<<4) + k)*65 + ci];
        acc[rr][0] += xv*w.x; acc[rr][1] += xv*w.y;
        acc[rr][2] += xv*w.z; acc[rr][3] += xv*w.w;
      }
    }
  }
  float4 b = ((const float4*)bias)[cg];
  #pragma unroll
  for (int rr=0;rr<8;rr++){
    int row = r0 + rg + (rr<<4);
    if (row < n){
      float4 v;
      v.x = acc[rr][0]+b.x; v.y = acc[rr][1]+b.y; v.z = acc[rr][2]+b.z; v.w = acc[rr][3]+b.w;
      if (do_relu){ v.x=fmaxf(v.x,0.f); v.y=fmaxf(v.y,0.f); v.z=fmaxf(v.z,0.f); v.w=fmaxf(v.w,0.f); }
      *(float4*)&outp[(size_t)row*64 + (cg<<2)] = v;
    }
  }
}

// concat [x1 | y2[inv]] -> cat[N,128]
__global__ void k_cat(const float* __restrict__ x1, const float* __restrict__ y2,
                      const int* __restrict__ inv, float* __restrict__ cat, int n){
  int idx = blockIdx.x*256 + threadIdx.x;
  if (idx < n*128){
    int i = idx>>7, c = idx&127;
    cat[idx] = (c < 64) ? x1[(size_t)i*64 + c] : y2[(size_t)inv[i]*64 + (c-64)];
  }
}

__global__ void k_lsm(const float* __restrict__ logits, const float* __restrict__ bl,
                      float* __restrict__ outp, int n){
  int wid = blockIdx.x*4 + (threadIdx.x>>6);
  int lane = threadIdx.x & 63;
  if (wid >= n) return;
  float v = logits[(size_t)wid*64 + lane] + bl[lane];
  float m = v;
  for (int o=32;o>0;o>>=1) m = fmaxf(m, __shfl_xor(m, o));
  float ex = expf(v - m);
  float s = ex;
  for (int o=32;o>0;o>>=1) s += __shfl_xor(s, o);
  outp[(size_t)wid*64 + lane] = v - m - logf(s);
}

// ---------------- launch ----------------
extern "C" void kernel_launch(void* const* d_in, const int* in_sizes, int n_in,
                              void* d_out, int out_size, void* d_ws, size_t ws_size,
                              hipStream_t stream) {
  const float* x   = (const float*)d_in[0];
  const int*   ei  = (const int*)d_in[1];
  const float* W1  = (const float*)d_in[2];
  const float* b1  = (const float*)d_in[3];
  const float* W2  = (const float*)d_in[4];
  const float* b2  = (const float*)d_in[5];
  const float* Wp  = (const float*)d_in[6];
  const float* bp  = (const float*)d_in[7];
  const float* cw1 = (const float*)d_in[8];
  const float* cb1 = (const float*)d_in[9];
  const float* cw2 = (const float*)d_in[10];
  const float* cb2 = (const float*)d_in[11];
  const float* Wl  = (const float*)d_in[12];
  const float* bl  = (const float*)d_in[13];
  float* out = (float*)d_out;

  const int n = in_sizes[0] / NF_IN;        // 100000
  const int e_total = in_sizes[1] / 2;      // 3200000
  const int* srcp = ei;
  const int* dstp = ei + e_total;

  char* ws = (char*)d_ws;
  size_t off = 0;
  auto take = [&](size_t bytes)->char* {
    char* p = ws + off; off = (off + bytes + 255) & ~(size_t)255; return p;
  };
  const int NB = (n + 1023) / 1024;         // 98
  int*      cnt    = (int*)     take((size_t)n*4);
  int*      rowptr = (int*)     take((size_t)n*4);
  int*      cursor = (int*)     take((size_t)n*4);
  float*    dinv   = (float*)   take((size_t)n*4);
  float*    g      = (float*)   take((size_t)n*4);
  int*      inv    = (int*)     take((size_t)n*4);
  unsigned* keys0  = (unsigned*)take((size_t)n*4);
  unsigned* vals0  = (unsigned*)take((size_t)n*4);
  unsigned* keys1  = (unsigned*)take((size_t)n*4);
  unsigned* vals1  = (unsigned*)take((size_t)n*4);
  int*      ghist  = (int*)     take((size_t)(16*NB)*4);
  int*      bsum   = (int*)     take((size_t)NB*4 + 256);
  int*      csr    = (int*)     take((size_t)e_total*4);
  float*    wT1    = (float*)   take(20480*4);
  float*    wT2    = (float*)   take(20480*4);
  float*    bigA   = (float*)   take((size_t)n*256*4);
  float*    bigB   = (float*)   take((size_t)n*256*4);
  float* u1  = bigA;
  float* h   = bigB;
  float* u2  = bigA;
  float* x1  = bigA + (size_t)n*64;
  float* ssx = bigA + (size_t)n*128;
  float* y1  = bigA + (size_t)n*192;
  float* y2  = bigB;
  float* cat = bigB + (size_t)n*64;
  float* logits = bigB + (size_t)n*192;

  const int nb64  = (n + 63) / 64;
  const int nb128 = (n + 127) / 128;
  const int nbAgg = (n + 3) / 4;
  const int nbE   = (e_total + 255) / 256;

  hipMemsetAsync(cnt, 0, (size_t)n*4, stream);
  k_hist<<<nbE, 256, 0, stream>>>(dstp, cnt, e_total);
  k_dinv<<<(n+255)/256, 256, 0, stream>>>(cnt, dinv, n);
  k_scanA<<<NB, 256, 0, stream>>>(cnt, n, bsum);
  k_scan1<<<1, 256, 0, stream>>>(bsum, NB);
  k_scanC<<<NB, 256, 0, stream>>>(cnt, n, bsum, rowptr, cursor);
  k_csr<<<nbE, 256, 0, stream>>>(srcp, dstp, cursor, csr, e_total);

  // GCN layer 1: u1 = dinv .* (x @ W1); h = relu(agg(u1) + b1)
  k_gemm128<<<dim3(nb128, 2), 256, 0, stream>>>(x, NF_IN, W1, NHID, u1, NHID, n, NF_IN, dinv);
  k_agg1<<<nbAgg, 256, 0, stream>>>(u1, rowptr, cnt, csr, dinv, b1, h, n);

  // GCN layer 2: u2 = dinv .* (h @ W2); x1 = agg(u2) + b2
  k_gemm<<<dim3(nb64, 1), 256, 0, stream>>>(h, NHID, W2, NC, u2, NC, n, NHID, dinv);
  k_agg2<<<nbAgg, 256, 0, stream>>>(u2, rowptr, cnt, csr, dinv, b2, x1, n);

  // score + sort keys
  k_gscore<<<nbAgg, 256, 0, stream>>>(x1, Wp, bp, g, keys0, vals0, n);

  // stable radix sort, 8 x 4-bit passes
  unsigned *ka = keys0, *va = vals0, *kb = keys1, *vb = vals1;
  for (int p = 0; p < 8; p++){
    k_rhist<<<NB, 256, 0, stream>>>(ka, p*4, ghist, n);
    k_scan1<<<1, 256, 0, stream>>>(ghist, 16*NB);
    k_rscatter<<<NB, 256, 0, stream>>>(ka, va, p*4, ghist, kb, vb, n);
    unsigned* tk = ka; ka = kb; kb = tk;
    unsigned* tv = va; va = vb; vb = tv;
  }

  // sorted sequence + inverse permutation (va = sorted node indices)
  k_ssx<<<(n*64+255)/256, 256, 0, stream>>>(va, g, x1, ssx, inv, n);

  // conv1d x2
  k_wt<<<(2*20480+255)/256, 256, 0, stream>>>(cw1, cw2, wT1, wT2);
  k_conv<<<(n+127)/128, 256, 0, stream>>>(ssx, wT1, cb1, y1, n, 1);
  k_conv<<<(n+127)/128, 256, 0, stream>>>(y1, wT2, cb2, y2, n, 0);

  // concat -> GEMM -> log_softmax
  k_cat<<<(n*128+255)/256, 256, 0, stream>>>(x1, y2, inv, cat, n);
  k_gemm<<<dim3(nb64, 1), 256, 0, stream>>>(cat, 2*NC, Wl, NC, logits, NC, n, 2*NC, nullptr);
  k_lsm<<<nbAgg, 256, 0, stream>>>(logits, bl, out, n);
}